// Round 5
// baseline (2075.811 us; speedup 1.0000x reference)
//
#include <hip/hip_runtime.h>
#include <hip/hip_bf16.h>

#define TOK 9216   // 96*96 tokens per image

// ---------------- workspace layout (in floats) ----------------
#define OFF_F1   0u
#define SZ_F1    (4u*64u*TOK)            // conv1 out  [img][64][9216]
#define OFF_FEAT (OFF_F1 + SZ_F1)
#define SZ_FEAT  (2u*128u*TOK)           // conv2 out, permuted: [b][c*2+n][9216]
#define OFF_Q    (OFF_FEAT + SZ_FEAT)
#define SZ_QKV   (2u*64u*TOK)
#define OFF_K    (OFF_Q + SZ_QKV)
#define OFF_V    (OFF_K + SZ_QKV)
#define OFF_W1   (OFF_V + SZ_QKV)        // [64][9] f32
#define OFF_B1   (OFF_W1 + 576u)
#define OFF_W2T  (OFF_B1 + 64u)          // [ci][9][co] f32 (transposed)
#define OFF_B2   (OFF_W2T + 36864u)
#define OFF_WCAT (OFF_B2 + 64u)          // [192][128] f32 (q;k;v)
#define OFF_BCAT (OFF_WCAT + 24576u)     // [192]

// ---------------- weight prep: copy/transpose f32 weights ----------------
__global__ __launch_bounds__(256) void prep_kernel(
    const float* __restrict__ w1, const float* __restrict__ b1,
    const float* __restrict__ w2, const float* __restrict__ b2,
    const float* __restrict__ qw, const float* __restrict__ qb,
    const float* __restrict__ kw, const float* __restrict__ kb,
    const float* __restrict__ vw, const float* __restrict__ vb,
    float* __restrict__ ws)
{
    int gid = blockIdx.x * 256 + threadIdx.x;   // 144*256 = 36864 threads
    if (gid < 576) ws[OFF_W1 + gid] = w1[gid];
    if (gid < 64) {
        ws[OFF_B1 + gid] = b1[gid];
        ws[OFF_B2 + gid] = b2[gid];
    }
    if (gid < 36864) {   // w2[co][ci][tap] -> w2t[ci][tap][co]
        int co = gid / 576; int rem = gid % 576;
        int ci = rem / 9;  int tp = rem % 9;
        ws[OFF_W2T + (ci*9 + tp)*64 + co] = w2[gid];
    }
    if (gid < 24576) {   // concat q/k/v weights
        int o = gid >> 7; int c = gid & 127;
        float v;
        if (o < 64)       v = qw[o*128 + c];
        else if (o < 128) v = kw[(o-64)*128 + c];
        else              v = vw[(o-128)*128 + c];
        ws[OFF_WCAT + gid] = v;
    }
    if (gid < 192) {
        float v;
        if (gid < 64)       v = qb[gid];
        else if (gid < 128) v = kb[gid-64];
        else                v = vb[gid-128];
        ws[OFF_BCAT + gid] = v;
    }
}

// ---------------- conv1: 1->64 ch, 3x3, relu ----------------
__global__ __launch_bounds__(256) void conv1_kernel(
    const float* __restrict__ x, float* __restrict__ ws)
{
    const float* w1f = ws + OFF_W1;
    const float* b1f = ws + OFF_B1;
    float* f1 = ws + OFF_F1;
    int gid = blockIdx.x * 256 + threadIdx.x;   // 4*9216
    int img = gid / TOK;
    int p   = gid % TOK;
    int h = p / 96, w = p % 96;
    float xv[9];
    #pragma unroll
    for (int dh = 0; dh < 3; ++dh)
        #pragma unroll
        for (int dw = 0; dw < 3; ++dw) {
            int r = h + dh - 1, c = w + dw - 1;
            bool ok = (r >= 0) && (r < 96) && (c >= 0) && (c < 96);
            xv[dh*3 + dw] = ok ? x[img*TOK + r*96 + c] : 0.f;
        }
    for (int co = 0; co < 64; ++co) {
        float a = b1f[co];
        #pragma unroll
        for (int t = 0; t < 9; ++t) a += w1f[co*9 + t] * xv[t];
        f1[(size_t)(img*64 + co)*TOK + p] = fmaxf(a, 0.f);
    }
}

// ---------------- conv2: 64->64 ch, 3x3, relu; writes permuted feat ----------------
__global__ __launch_bounds__(256) void conv2_kernel(float* __restrict__ ws)
{
    __align__(16) __shared__ float sT[64 * 156];   // [ci][3 rows][52 (50 used)]
    const float* f1  = ws + OFF_F1;
    const float* w2t = ws + OFF_W2T;
    const float* b2f = ws + OFF_B2;
    float* feat = ws + OFF_FEAT;

    int bid = blockIdx.x;            // 4 img * 96 rows * 2 strips = 768
    int img = bid / 192;
    int rem = bid % 192;
    int h  = rem >> 1;
    int s2 = rem & 1;
    int tid = threadIdx.x;

    // stage f1: 64 ci x 3 rows x 50 cols (halo=1)
    for (int idx = tid; idx < 9600; idx += 256) {
        int ci = idx / 150;
        int r2 = idx % 150;
        int r = r2 / 50, cc = r2 % 50;
        int row = h - 1 + r, col = s2*48 - 1 + cc;
        float v = 0.f;
        if (row >= 0 && row < 96 && col >= 0 && col < 96)
            v = f1[(size_t)(img*64 + ci)*TOK + row*96 + col];
        sT[ci*156 + r*52 + cc] = v;
    }
    __syncthreads();

    int co = tid & 63, g = tid >> 6;
    int px0 = g * 12;                 // 4 groups x 12 px = 48-px strip
    float acc[12];
    float bb = b2f[co];
    #pragma unroll
    for (int j = 0; j < 12; ++j) acc[j] = bb;

    for (int ci = 0; ci < 64; ++ci) {
        float wv[9];
        #pragma unroll
        for (int t = 0; t < 9; ++t) wv[t] = w2t[(ci*9 + t)*64 + co];   // coalesced
        #pragma unroll
        for (int r = 0; r < 3; ++r) {
            const float4* tp4 = (const float4*)&sT[ci*156 + r*52 + px0];
            float4 a0 = tp4[0], a1 = tp4[1], a2 = tp4[2], a3 = tp4[3]; // broadcast reads
            float t16[16] = {a0.x,a0.y,a0.z,a0.w, a1.x,a1.y,a1.z,a1.w,
                             a2.x,a2.y,a2.z,a2.w, a3.x,a3.y,a3.z,a3.w};
            #pragma unroll
            for (int dw = 0; dw < 3; ++dw) {
                float wgt = wv[r*3 + dw];
                #pragma unroll
                for (int j = 0; j < 12; ++j) acc[j] += wgt * t16[j + dw];
            }
        }
    }
    int b = img >> 1, n = img & 1;
    int colbase = s2*48 + px0;
    #pragma unroll
    for (int j = 0; j < 12; ++j)
        feat[(size_t)(b*128 + co*2 + n)*TOK + h*96 + colbase + j] = fmaxf(acc[j], 0.f);
}

// ---------------- fused 1x1 QKV: [192 out][128 in] GEMV per token ----------------
__global__ __launch_bounds__(256) void qkv_kernel(float* __restrict__ ws)
{
    const float* feat = ws + OFF_FEAT;
    const float* wcat = ws + OFF_WCAT;
    const float* bcat = ws + OFF_BCAT;
    int bid = blockIdx.x;            // 2 * 36 * 48 = 3456
    int b   = bid / (36*48);
    int rem = bid % (36*48);
    int tg  = rem / 48;
    int og  = rem % 48;
    int tid = threadIdx.x;
    int o    = og*4 + (tid >> 6);    // wave-uniform output row
    int lane = tid & 63;
    int t0   = tg*256 + lane*4;
    const float* fb   = feat + (size_t)b*128*TOK;
    const float* wrow = wcat + o*128;
    float a0, a1, a2, a3;
    a0 = a1 = a2 = a3 = bcat[o];
    for (int c = 0; c < 128; ++c) {
        float4 fv = *(const float4*)&fb[(size_t)c*TOK + t0];
        float w = wrow[c];           // scalar (wave-uniform)
        a0 += w*fv.x; a1 += w*fv.y; a2 += w*fv.z; a3 += w*fv.w;
    }
    float* dst;
    if (o < 64)       dst = ws + OFF_Q + ((size_t)b*64 + o      )*TOK;
    else if (o < 128) dst = ws + OFF_K + ((size_t)b*64 + (o-64 ))*TOK;
    else              dst = ws + OFF_V + ((size_t)b*64 + (o-128))*TOK;
    float4 out4 = {a0, a1, a2, a3};
    *(float4*)&dst[t0] = out4;
}

// ---------------- flash attention (f32 VALU baseline) ----------------
// block = (b, 64-query tile); 256 thr = 64 q-lanes x 4 d-groups of 16
__global__ __launch_bounds__(256) void attn_kernel(
    const float* __restrict__ ws, float* __restrict__ out)
{
    __align__(16) __shared__ float Ks[64*64];    // [d][k]
    __align__(16) __shared__ float Vt[64*68];    // [k][d], stride 68 (16B-aligned rows)
    __align__(16) __shared__ float P [64*65];    // [q][k], stride 65 (conflict-free)
    __shared__ float redmax[256];
    __shared__ float redsum[256];

    int bid = blockIdx.x;            // 2 * 144
    int b  = bid / 144;
    int qt = bid % 144;
    int tid = threadIdx.x;
    int q = tid & 63;
    int g = tid >> 6;
    int q0 = qt * 64;
    const float* Qg = ws + OFF_Q + (size_t)b*64*TOK;
    const float* Kg = ws + OFF_K + (size_t)b*64*TOK;
    const float* Vg = ws + OFF_V + (size_t)b*64*TOK;

    float qreg[64];                  // Q column for this lane, scale folded in
    #pragma unroll
    for (int d = 0; d < 64; ++d) qreg[d] = Qg[(size_t)d*TOK + q0 + q] * 0.125f;

    float O[16];
    #pragma unroll
    for (int j = 0; j < 16; ++j) O[j] = 0.f;
    float m = -INFINITY, l = 0.f;

    for (int kb = 0; kb < 144; ++kb) {
        __syncthreads();             // A: prev-iter LDS reads complete
        #pragma unroll
        for (int i = 0; i < 4; ++i) {
            int idx = tid + i*256;   // 1024 float4 loads cover K and V tiles
            int d  = idx >> 4;
            int kq = idx & 15;
            const float4 kv = *(const float4*)&Kg[(size_t)d*TOK + kb*64 + kq*4];
            *(float4*)&Ks[d*64 + kq*4] = kv;
            const float4 vv = *(const float4*)&Vg[(size_t)d*TOK + kb*64 + kq*4];
            Vt[(kq*4+0)*68 + d] = vv.x;
            Vt[(kq*4+1)*68 + d] = vv.y;
            Vt[(kq*4+2)*68 + d] = vv.z;
            Vt[(kq*4+3)*68 + d] = vv.w;
        }
        __syncthreads();             // B: staging visible

        float s[16];
        #pragma unroll
        for (int j = 0; j < 16; ++j) s[j] = 0.f;
        #pragma unroll
        for (int d = 0; d < 64; ++d) {
            float qv = qreg[d];
            const float4* kp = (const float4*)&Ks[d*64 + g*16];  // broadcast
            float4 k0 = kp[0], k1 = kp[1], k2 = kp[2], k3 = kp[3];
            s[0] += qv*k0.x; s[1] += qv*k0.y; s[2]  += qv*k0.z; s[3]  += qv*k0.w;
            s[4] += qv*k1.x; s[5] += qv*k1.y; s[6]  += qv*k1.z; s[7]  += qv*k1.w;
            s[8] += qv*k2.x; s[9] += qv*k2.y; s[10] += qv*k2.z; s[11] += qv*k2.w;
            s[12]+= qv*k3.x; s[13]+= qv*k3.y; s[14] += qv*k3.z; s[15] += qv*k3.w;
        }
        float pm = s[0];
        #pragma unroll
        for (int j = 1; j < 16; ++j) pm = fmaxf(pm, s[j]);
        redmax[g*64 + q] = pm;
        __syncthreads();             // C: block max ready
        float mb = fmaxf(fmaxf(redmax[q], redmax[64+q]), fmaxf(redmax[128+q], redmax[192+q]));
        float mnew = fmaxf(m, mb);
        float fs = __expf(m - mnew);
        float psum = 0.f;
        #pragma unroll
        for (int j = 0; j < 16; ++j) { float p = __expf(s[j] - mnew); s[j] = p; psum += p; }
        redsum[g*64 + q] = psum;
        #pragma unroll
        for (int j = 0; j < 16; ++j) P[q*65 + g*16 + j] = s[j];
        __syncthreads();             // D: P + sums ready
        float lb = redsum[q] + redsum[64+q] + redsum[128+q] + redsum[192+q];
        l = l*fs + lb;
        m = mnew;
        #pragma unroll
        for (int j = 0; j < 16; ++j) O[j] *= fs;
        #pragma unroll 4
        for (int k = 0; k < 64; ++k) {
            float pk = P[q*65 + k];                              // conflict-free
            const float4* vp = (const float4*)&Vt[k*68 + g*16];  // broadcast
            float4 v0 = vp[0], v1 = vp[1], v2 = vp[2], v3 = vp[3];
            O[0] += pk*v0.x; O[1] += pk*v0.y; O[2]  += pk*v0.z; O[3]  += pk*v0.w;
            O[4] += pk*v1.x; O[5] += pk*v1.y; O[6]  += pk*v1.z; O[7]  += pk*v1.w;
            O[8] += pk*v2.x; O[9] += pk*v2.y; O[10] += pk*v2.z; O[11] += pk*v2.w;
            O[12]+= pk*v3.x; O[13]+= pk*v3.y; O[14] += pk*v3.z; O[15] += pk*v3.w;
        }
    }
    float inv = 1.f / l;
    #pragma unroll
    for (int j = 0; j < 16; ++j)
        out[(size_t)(b*64 + g*16 + j)*TOK + q0 + q] = O[j] * inv;
}

extern "C" void kernel_launch(void* const* d_in, const int* in_sizes, int n_in,
                              void* d_out, int out_size, void* d_ws, size_t ws_size,
                              hipStream_t stream)
{
    const float* frames = (const float*)d_in[0];
    const float* w1 = (const float*)d_in[1];
    const float* b1 = (const float*)d_in[2];
    const float* w2 = (const float*)d_in[3];
    const float* b2 = (const float*)d_in[4];
    const float* qw = (const float*)d_in[5];
    const float* qb = (const float*)d_in[6];
    const float* kw = (const float*)d_in[7];
    const float* kb = (const float*)d_in[8];
    const float* vw = (const float*)d_in[9];
    const float* vb = (const float*)d_in[10];
    float* ws = (float*)d_ws;
    float* out = (float*)d_out;

    hipLaunchKernelGGL(prep_kernel, dim3(144), dim3(256), 0, stream,
                       w1, b1, w2, b2, qw, qb, kw, kb, vw, vb, ws);
    hipLaunchKernelGGL(conv1_kernel, dim3(144), dim3(256), 0, stream, frames, ws);
    hipLaunchKernelGGL(conv2_kernel, dim3(768), dim3(256), 0, stream, ws);
    hipLaunchKernelGGL(qkv_kernel, dim3(3456), dim3(256), 0, stream, ws);
    hipLaunchKernelGGL(attn_kernel, dim3(288), dim3(256), 0, stream, ws, out);
}

// Round 6
// 601.007 us; speedup vs baseline: 3.4539x; 3.4539x over previous
//
#include <hip/hip_runtime.h>
#include <hip/hip_bf16.h>

#define TOK 9216   // 96*96 tokens per image

typedef _Float16 half8 __attribute__((ext_vector_type(8)));
typedef float f32x4 __attribute__((ext_vector_type(4)));

// ---------------- workspace layout (in floats) ----------------
#define OFF_F1   0u
#define SZ_F1    (4u*64u*TOK)            // conv1 out  [img][64][9216]
#define OFF_FEAT (OFF_F1 + SZ_F1)
#define SZ_FEAT  (2u*128u*TOK)           // conv2 out, permuted: [b][c*2+n][9216]
#define OFF_Q    (OFF_FEAT + SZ_FEAT)
#define SZ_QKV   (2u*64u*TOK)
#define OFF_K    (OFF_Q + SZ_QKV)
#define OFF_V    (OFF_K + SZ_QKV)
#define OFF_W1   (OFF_V + SZ_QKV)        // [64][9] f32
#define OFF_B1   (OFF_W1 + 576u)
#define OFF_W2T  (OFF_B1 + 64u)          // [ci][9][co] f32 (transposed)
#define OFF_B2   (OFF_W2T + 36864u)
#define OFF_WCAT (OFF_B2 + 64u)          // [192][128] f32 (q;k;v)
#define OFF_BCAT (OFF_WCAT + 24576u)     // [192]

// f16 QKV overlaid on F1 (dead after conv2). Offsets in f32 units.
#define OFF_QT   OFF_F1                  // [b][t][64] f16, scale folded
#define OFF_KT   (OFF_F1 + 589824u)      // [b][t][64] f16
#define OFF_VH   (OFF_F1 + 1179648u)     // [b][64][t] f16

// ---------------- weight prep: copy/transpose f32 weights ----------------
__global__ __launch_bounds__(256) void prep_kernel(
    const float* __restrict__ w1, const float* __restrict__ b1,
    const float* __restrict__ w2, const float* __restrict__ b2,
    const float* __restrict__ qw, const float* __restrict__ qb,
    const float* __restrict__ kw, const float* __restrict__ kb,
    const float* __restrict__ vw, const float* __restrict__ vb,
    float* __restrict__ ws)
{
    int gid = blockIdx.x * 256 + threadIdx.x;
    if (gid < 576) ws[OFF_W1 + gid] = w1[gid];
    if (gid < 64) {
        ws[OFF_B1 + gid] = b1[gid];
        ws[OFF_B2 + gid] = b2[gid];
    }
    if (gid < 36864) {   // w2[co][ci][tap] -> w2t[ci][tap][co]
        int co = gid / 576; int rem = gid % 576;
        int ci = rem / 9;  int tp = rem % 9;
        ws[OFF_W2T + (ci*9 + tp)*64 + co] = w2[gid];
    }
    if (gid < 24576) {
        int o = gid >> 7; int c = gid & 127;
        float v;
        if (o < 64)       v = qw[o*128 + c];
        else if (o < 128) v = kw[(o-64)*128 + c];
        else              v = vw[(o-128)*128 + c];
        ws[OFF_WCAT + gid] = v;
    }
    if (gid < 192) {
        float v;
        if (gid < 64)       v = qb[gid];
        else if (gid < 128) v = kb[gid-64];
        else                v = vb[gid-128];
        ws[OFF_BCAT + gid] = v;
    }
}

// ---------------- conv1: 1->64 ch, 3x3, relu ----------------
__global__ __launch_bounds__(256) void conv1_kernel(
    const float* __restrict__ x, float* __restrict__ ws)
{
    const float* w1f = ws + OFF_W1;
    const float* b1f = ws + OFF_B1;
    float* f1 = ws + OFF_F1;
    int gid = blockIdx.x * 256 + threadIdx.x;
    int img = gid / TOK;
    int p   = gid % TOK;
    int h = p / 96, w = p % 96;
    float xv[9];
    #pragma unroll
    for (int dh = 0; dh < 3; ++dh)
        #pragma unroll
        for (int dw = 0; dw < 3; ++dw) {
            int r = h + dh - 1, c = w + dw - 1;
            bool ok = (r >= 0) && (r < 96) && (c >= 0) && (c < 96);
            xv[dh*3 + dw] = ok ? x[img*TOK + r*96 + c] : 0.f;
        }
    for (int co = 0; co < 64; ++co) {
        float a = b1f[co];
        #pragma unroll
        for (int t = 0; t < 9; ++t) a += w1f[co*9 + t] * xv[t];
        f1[(size_t)(img*64 + co)*TOK + p] = fmaxf(a, 0.f);
    }
}

// ---------------- conv2: 64->64 ch, 3x3, relu; writes permuted feat ----------------
__global__ __launch_bounds__(256) void conv2_kernel(float* __restrict__ ws)
{
    __align__(16) __shared__ float sT[64 * 156];
    const float* f1  = ws + OFF_F1;
    const float* w2t = ws + OFF_W2T;
    const float* b2f = ws + OFF_B2;
    float* feat = ws + OFF_FEAT;

    int bid = blockIdx.x;            // 4 img * 96 rows * 2 strips = 768
    int img = bid / 192;
    int rem = bid % 192;
    int h  = rem >> 1;
    int s2 = rem & 1;
    int tid = threadIdx.x;

    for (int idx = tid; idx < 9600; idx += 256) {
        int ci = idx / 150;
        int r2 = idx % 150;
        int r = r2 / 50, cc = r2 % 50;
        int row = h - 1 + r, col = s2*48 - 1 + cc;
        float v = 0.f;
        if (row >= 0 && row < 96 && col >= 0 && col < 96)
            v = f1[(size_t)(img*64 + ci)*TOK + row*96 + col];
        sT[ci*156 + r*52 + cc] = v;
    }
    __syncthreads();

    int co = tid & 63, g = tid >> 6;
    int px0 = g * 12;
    float acc[12];
    float bb = b2f[co];
    #pragma unroll
    for (int j = 0; j < 12; ++j) acc[j] = bb;

    for (int ci = 0; ci < 64; ++ci) {
        float wv[9];
        #pragma unroll
        for (int t = 0; t < 9; ++t) wv[t] = w2t[(ci*9 + t)*64 + co];
        #pragma unroll
        for (int r = 0; r < 3; ++r) {
            const float4* tp4 = (const float4*)&sT[ci*156 + r*52 + px0];
            float4 a0 = tp4[0], a1 = tp4[1], a2 = tp4[2], a3 = tp4[3];
            float t16[16] = {a0.x,a0.y,a0.z,a0.w, a1.x,a1.y,a1.z,a1.w,
                             a2.x,a2.y,a2.z,a2.w, a3.x,a3.y,a3.z,a3.w};
            #pragma unroll
            for (int dw = 0; dw < 3; ++dw) {
                float wgt = wv[r*3 + dw];
                #pragma unroll
                for (int j = 0; j < 12; ++j) acc[j] += wgt * t16[j + dw];
            }
        }
    }
    int b = img >> 1, n = img & 1;
    int colbase = s2*48 + px0;
    #pragma unroll
    for (int j = 0; j < 12; ++j)
        feat[(size_t)(b*128 + co*2 + n)*TOK + h*96 + colbase + j] = fmaxf(acc[j], 0.f);
}

// ---------------- fused 1x1 QKV: [192 out][128 in] GEMV per token ----------------
__global__ __launch_bounds__(256) void qkv_kernel(float* __restrict__ ws)
{
    const float* feat = ws + OFF_FEAT;
    const float* wcat = ws + OFF_WCAT;
    const float* bcat = ws + OFF_BCAT;
    int bid = blockIdx.x;            // 2 * 36 * 48 = 3456
    int b   = bid / (36*48);
    int rem = bid % (36*48);
    int tg  = rem / 48;
    int og  = rem % 48;
    int tid = threadIdx.x;
    int o    = og*4 + (tid >> 6);
    int lane = tid & 63;
    int t0   = tg*256 + lane*4;
    const float* fb   = feat + (size_t)b*128*TOK;
    const float* wrow = wcat + o*128;
    float a0, a1, a2, a3;
    a0 = a1 = a2 = a3 = bcat[o];
    for (int c = 0; c < 128; ++c) {
        float4 fv = *(const float4*)&fb[(size_t)c*TOK + t0];
        float w = wrow[c];
        a0 += w*fv.x; a1 += w*fv.y; a2 += w*fv.z; a3 += w*fv.w;
    }
    float* dst;
    if (o < 64)       dst = ws + OFF_Q + ((size_t)b*64 + o      )*TOK;
    else if (o < 128) dst = ws + OFF_K + ((size_t)b*64 + (o-64 ))*TOK;
    else              dst = ws + OFF_V + ((size_t)b*64 + (o-128))*TOK;
    float4 out4 = {a0, a1, a2, a3};
    *(float4*)&dst[t0] = out4;
}

// ---------------- cvt: f32 [d][t] -> f16 tiles for MFMA ----------------
// blocks 0..575:   Q,K -> [t][64] f16 (transpose via LDS); Q scaled by 0.125
// blocks 576..1727: V -> [d][t] f16 (straight convert)
__global__ __launch_bounds__(256) void cvt_kernel(float* __restrict__ ws)
{
    __shared__ __align__(16) float lds[64*68];
    int bid = blockIdx.x;
    int tid = threadIdx.x;
    if (bid < 576) {
        int tensor = bid / 288;          // 0=Q, 1=K
        int rem = bid % 288;
        int b = rem / 144, tile = rem % 144;
        int t0 = tile * 64;
        const float* src = ws + (tensor ? OFF_K : OFF_Q) + (size_t)b*64*TOK;
        _Float16* dst = (_Float16*)(ws + (tensor ? OFF_KT : OFF_QT)) + (size_t)b*TOK*64;
        float scale = tensor ? 1.0f : 0.125f;
        int d = tid >> 2, seg = tid & 3;
        #pragma unroll
        for (int j = 0; j < 4; ++j) {
            float4 v = *(const float4*)&src[(size_t)d*TOK + t0 + seg*16 + j*4];
            *(float4*)&lds[d*68 + seg*16 + j*4] = v;
        }
        __syncthreads();
        int t = tid >> 2, dseg = tid & 3;
        __align__(16) _Float16 h[16];
        #pragma unroll
        for (int e = 0; e < 16; ++e)
            h[e] = (_Float16)(lds[(dseg*16 + e)*68 + t] * scale);
        *(uint4*)&dst[(size_t)(t0 + t)*64 + dseg*16]     = *(uint4*)&h[0];
        *(uint4*)&dst[(size_t)(t0 + t)*64 + dseg*16 + 8] = *(uint4*)&h[8];
    } else {
        size_t idx = (size_t)(bid - 576) * 1024 + tid * 4;   // over 2*64*TOK
        const float* src = ws + OFF_V;
        _Float16* dst = (_Float16*)(ws + OFF_VH);
        float4 v = *(const float4*)&src[idx];
        union { _Float16 h[4]; uint2 u; } pk;
        pk.h[0] = (_Float16)v.x; pk.h[1] = (_Float16)v.y;
        pk.h[2] = (_Float16)v.z; pk.h[3] = (_Float16)v.w;
        *(uint2*)&dst[idx] = pk.u;
    }
}

// ---------------- flash attention, f16 MFMA ----------------
// 256 thr = 4 waves x 16 q-rows; KVBLK=64; K/V/P in XOR-swizzled LDS.
// S tile per wave: D[q][kt]: col kt = lane&15, row q = 4*(lane>>4)+reg.
__global__ __launch_bounds__(256) void attn_kernel(
    const float* __restrict__ ws, float* __restrict__ out)
{
    __shared__ __align__(16) char smem[24576];
    char* sK = smem;            // [64 kt][64 d] f16, byte^((kt&7)<<4)
    char* sV = smem + 8192;     // [64 c ][64 m] f16, byte^((c&7)<<4)
    char* sP = smem + 16384;    // [64 q ][64 m] f16, byte^((q&7)<<4)
    float* ldsf = (float*)smem; // epilogue reuse: [64 c][68] f32

    int bid = blockIdx.x;       // 2 * 144
    int b  = bid / 144;
    int qt = bid % 144;
    int tid = threadIdx.x;
    int lane = tid & 63, w = tid >> 6;
    int q0 = qt * 64;
    int lr = lane & 15;         // fragment row/col index
    int lk = lane >> 4;         // k-group (0..3)

    const _Float16* Qt = (const _Float16*)(ws + OFF_QT) + (size_t)b*TOK*64;
    const _Float16* Kt = (const _Float16*)(ws + OFF_KT) + (size_t)b*TOK*64;
    const _Float16* Vh = (const _Float16*)(ws + OFF_VH) + (size_t)b*64*TOK;

    // Q fragments in registers (A: row q = lr, k d = ch*32 + lk*8 + e)
    half8 qA[2];
    #pragma unroll
    for (int ch = 0; ch < 2; ++ch)
        qA[ch] = *(const half8*)&Qt[(size_t)(q0 + w*16 + lr)*64 + ch*32 + lk*8];

    f32x4 O[4];                 // [csub]: col c = csub*16+lr, row q = 4*lk+reg
    #pragma unroll
    for (int cs = 0; cs < 4; ++cs) O[cs] = (f32x4){0.f, 0.f, 0.f, 0.f};
    float mM[4], lS[4];
    #pragma unroll
    for (int r = 0; r < 4; ++r) { mM[r] = -INFINITY; lS[r] = 0.f; }

    for (int kb = 0; kb < 144; ++kb) {
        __syncthreads();        // prev-iter LDS reads complete
        // ---- stage K,V tiles (reg -> swizzled LDS) ----
        #pragma unroll
        for (int i = 0; i < 2; ++i) {
            int idx = tid + i*256;          // 512 x 16B covers both tiles
            int row = idx >> 3, seg = idx & 7;
            uint4 kv = *(const uint4*)&Kt[(size_t)(kb*64 + row)*64 + seg*8];
            *(uint4*)(sK + ((row*128 + seg*16) ^ ((row&7)<<4))) = kv;
            uint4 vv = *(const uint4*)&Vh[(size_t)row*TOK + kb*64 + seg*8];
            *(uint4*)(sV + ((row*128 + seg*16) ^ ((row&7)<<4))) = vv;
        }
        __syncthreads();        // staging visible

        // ---- QK^T: S[q 16][kt 64] per wave ----
        f32x4 S[4];
        #pragma unroll
        for (int st = 0; st < 4; ++st) S[st] = (f32x4){0.f, 0.f, 0.f, 0.f};
        #pragma unroll
        for (int st = 0; st < 4; ++st) {
            int t = st*16 + lr;
            #pragma unroll
            for (int ch = 0; ch < 2; ++ch) {
                half8 kB = *(const half8*)(sK + ((t*128 + ch*64 + lk*16) ^ ((t&7)<<4)));
                S[st] = __builtin_amdgcn_mfma_f32_16x16x32_f16(qA[ch], kB, S[st], 0, 0, 0);
            }
        }

        // ---- online softmax (wave-parallel; rows live on 16-lane groups) ----
        float pm[4];
        #pragma unroll
        for (int r = 0; r < 4; ++r)
            pm[r] = fmaxf(fmaxf(S[0][r], S[1][r]), fmaxf(S[2][r], S[3][r]));
        #pragma unroll
        for (int mk = 1; mk <= 8; mk <<= 1)
            #pragma unroll
            for (int r = 0; r < 4; ++r)
                pm[r] = fmaxf(pm[r], __shfl_xor(pm[r], mk));
        float fs[4];
        #pragma unroll
        for (int r = 0; r < 4; ++r) {
            float mn = fmaxf(mM[r], pm[r]);
            fs[r] = __expf(mM[r] - mn);
            mM[r] = mn;
        }
        float p[4][4], ps[4];
        #pragma unroll
        for (int r = 0; r < 4; ++r) ps[r] = 0.f;
        #pragma unroll
        for (int st = 0; st < 4; ++st)
            #pragma unroll
            for (int r = 0; r < 4; ++r) {
                p[st][r] = __expf(S[st][r] - mM[r]);
                ps[r] += p[st][r];
            }
        #pragma unroll
        for (int mk = 1; mk <= 8; mk <<= 1)
            #pragma unroll
            for (int r = 0; r < 4; ++r)
                ps[r] += __shfl_xor(ps[r], mk);
        #pragma unroll
        for (int r = 0; r < 4; ++r) lS[r] = lS[r]*fs[r] + ps[r];
        #pragma unroll
        for (int cs = 0; cs < 4; ++cs)
            #pragma unroll
            for (int r = 0; r < 4; ++r) O[cs][r] *= fs[r];

        // ---- P -> f16 pairs -> swizzled LDS (even lanes write u32) ----
        #pragma unroll
        for (int st = 0; st < 4; ++st)
            #pragma unroll
            for (int r = 0; r < 4; ++r) {
                union { _Float16 h; unsigned short u; } cv;
                cv.h = (_Float16)p[st][r];
                unsigned int bits = cv.u;
                unsigned int nb = (unsigned int)__shfl_xor((int)bits, 1);
                if ((lane & 1) == 0) {
                    int qrow = w*16 + 4*lk + r;
                    int m = st*16 + lr;          // even
                    *(unsigned int*)(sP + ((qrow*128 + m*2) ^ ((qrow&7)<<4))) =
                        bits | (nb << 16);
                }
            }
        __syncthreads();        // P visible

        // ---- PV: O[q 16][c 64] += P[16x64] * V^T ----
        #pragma unroll
        for (int ch = 0; ch < 2; ++ch) {
            int qrow = w*16 + lr;
            half8 pA = *(const half8*)(sP + ((qrow*128 + ch*64 + lk*16) ^ ((qrow&7)<<4)));
            #pragma unroll
            for (int cs = 0; cs < 4; ++cs) {
                int crow = cs*16 + lr;
                half8 vB = *(const half8*)(sV + ((crow*128 + ch*64 + lk*16) ^ ((crow&7)<<4)));
                O[cs] = __builtin_amdgcn_mfma_f32_16x16x32_f16(pA, vB, O[cs], 0, 0, 0);
            }
        }
    }

    // ---- epilogue: normalize, transpose via LDS, coalesced f32 writes ----
    __syncthreads();
    float inv[4];
    #pragma unroll
    for (int r = 0; r < 4; ++r) inv[r] = 1.f / lS[r];
    #pragma unroll
    for (int cs = 0; cs < 4; ++cs)
        #pragma unroll
        for (int r = 0; r < 4; ++r)
            ldsf[(cs*16 + lr)*68 + w*16 + 4*lk + r] = O[cs][r] * inv[r];
    __syncthreads();
    int c = tid >> 2, seg = tid & 3;
    const float* srcr = &ldsf[c*68 + seg*16];
    float* dstr = &out[(size_t)(b*64 + c)*TOK + q0 + seg*16];
    #pragma unroll
    for (int j = 0; j < 4; ++j)
        *(float4*)&dstr[j*4] = *(const float4*)&srcr[j*4];
}

extern "C" void kernel_launch(void* const* d_in, const int* in_sizes, int n_in,
                              void* d_out, int out_size, void* d_ws, size_t ws_size,
                              hipStream_t stream)
{
    const float* frames = (const float*)d_in[0];
    const float* w1 = (const float*)d_in[1];
    const float* b1 = (const float*)d_in[2];
    const float* w2 = (const float*)d_in[3];
    const float* b2 = (const float*)d_in[4];
    const float* qw = (const float*)d_in[5];
    const float* qb = (const float*)d_in[6];
    const float* kw = (const float*)d_in[7];
    const float* kb = (const float*)d_in[8];
    const float* vw = (const float*)d_in[9];
    const float* vb = (const float*)d_in[10];
    float* ws = (float*)d_ws;
    float* out = (float*)d_out;

    hipLaunchKernelGGL(prep_kernel, dim3(144), dim3(256), 0, stream,
                       w1, b1, w2, b2, qw, qb, kw, kb, vw, vb, ws);
    hipLaunchKernelGGL(conv1_kernel, dim3(144), dim3(256), 0, stream, frames, ws);
    hipLaunchKernelGGL(conv2_kernel, dim3(768), dim3(256), 0, stream, ws);
    hipLaunchKernelGGL(qkv_kernel, dim3(3456), dim3(256), 0, stream, ws);
    hipLaunchKernelGGL(cvt_kernel, dim3(1728), dim3(256), 0, stream, ws);
    hipLaunchKernelGGL(attn_kernel, dim3(288), dim3(256), 0, stream, ws, out);
}

// Round 7
// 408.776 us; speedup vs baseline: 5.0781x; 1.4703x over previous
//
#include <hip/hip_runtime.h>
#include <hip/hip_bf16.h>

#define TOK 9216   // 96*96 tokens per image
#define KSPLIT 4
#define KCHUNK 36  // 144 / KSPLIT

typedef _Float16 half8 __attribute__((ext_vector_type(8)));
typedef float f32x4 __attribute__((ext_vector_type(4)));

// ---------------- workspace layout (in floats) ----------------
#define OFF_F1   0u
#define SZ_F1    (4u*64u*TOK)            // conv1 out  [img][64][9216]
#define OFF_FEAT (OFF_F1 + SZ_F1)
#define SZ_FEAT  (2u*128u*TOK)           // conv2 out, permuted: [b][c*2+n][9216]
#define OFF_Q    (OFF_FEAT + SZ_FEAT)
#define SZ_QKV   (2u*64u*TOK)
#define OFF_K    (OFF_Q + SZ_QKV)
#define OFF_V    (OFF_K + SZ_QKV)
#define OFF_W1   (OFF_V + SZ_QKV)        // [64][9] f32
#define OFF_B1   (OFF_W1 + 576u)
#define OFF_W2T  (OFF_B1 + 64u)          // [ci][9][co] f32 (transposed)
#define OFF_B2   (OFF_W2T + 36864u)
#define OFF_WCAT (OFF_B2 + 64u)          // [192][128] f32 (q;k;v)
#define OFF_BCAT (OFF_WCAT + 24576u)     // [192]

// f16 QKV overlaid on F1 (dead after conv2). Offsets in f32 units.
#define OFF_QT   OFF_F1                  // [b][t][64] f16, scale folded
#define OFF_KT   (OFF_F1 + 589824u)      // [b][t][64] f16
#define OFF_VH   (OFF_F1 + 1179648u)     // [b][64][t] f16

// KV-split partials overlay FEAT..V f32 region (dead once attn runs;
// rewritten by conv2/qkv every replay before attn reads -> replay-safe).
#define OFF_PART OFF_FEAT                        // [b][ks][64 c][TOK] f32, unnormalized
#define OFF_ML   (OFF_PART + 2u*KSPLIT*64u*TOK)  // [b][ks][2 (m,l)][TOK] f32

// ---------------- weight prep: copy/transpose f32 weights ----------------
__global__ __launch_bounds__(256) void prep_kernel(
    const float* __restrict__ w1, const float* __restrict__ b1,
    const float* __restrict__ w2, const float* __restrict__ b2,
    const float* __restrict__ qw, const float* __restrict__ qb,
    const float* __restrict__ kw, const float* __restrict__ kb,
    const float* __restrict__ vw, const float* __restrict__ vb,
    float* __restrict__ ws)
{
    int gid = blockIdx.x * 256 + threadIdx.x;
    if (gid < 576) ws[OFF_W1 + gid] = w1[gid];
    if (gid < 64) {
        ws[OFF_B1 + gid] = b1[gid];
        ws[OFF_B2 + gid] = b2[gid];
    }
    if (gid < 36864) {   // w2[co][ci][tap] -> w2t[ci][tap][co]
        int co = gid / 576; int rem = gid % 576;
        int ci = rem / 9;  int tp = rem % 9;
        ws[OFF_W2T + (ci*9 + tp)*64 + co] = w2[gid];
    }
    if (gid < 24576) {
        int o = gid >> 7; int c = gid & 127;
        float v;
        if (o < 64)       v = qw[o*128 + c];
        else if (o < 128) v = kw[(o-64)*128 + c];
        else              v = vw[(o-128)*128 + c];
        ws[OFF_WCAT + gid] = v;
    }
    if (gid < 192) {
        float v;
        if (gid < 64)       v = qb[gid];
        else if (gid < 128) v = kb[gid-64];
        else                v = vb[gid-128];
        ws[OFF_BCAT + gid] = v;
    }
}

// ---------------- conv1: 1->64 ch, 3x3, relu ----------------
__global__ __launch_bounds__(256) void conv1_kernel(
    const float* __restrict__ x, float* __restrict__ ws)
{
    const float* w1f = ws + OFF_W1;
    const float* b1f = ws + OFF_B1;
    float* f1 = ws + OFF_F1;
    int gid = blockIdx.x * 256 + threadIdx.x;
    int img = gid / TOK;
    int p   = gid % TOK;
    int h = p / 96, w = p % 96;
    float xv[9];
    #pragma unroll
    for (int dh = 0; dh < 3; ++dh)
        #pragma unroll
        for (int dw = 0; dw < 3; ++dw) {
            int r = h + dh - 1, c = w + dw - 1;
            bool ok = (r >= 0) && (r < 96) && (c >= 0) && (c < 96);
            xv[dh*3 + dw] = ok ? x[img*TOK + r*96 + c] : 0.f;
        }
    for (int co = 0; co < 64; ++co) {
        float a = b1f[co];
        #pragma unroll
        for (int t = 0; t < 9; ++t) a += w1f[co*9 + t] * xv[t];
        f1[(size_t)(img*64 + co)*TOK + p] = fmaxf(a, 0.f);
    }
}

// ---------------- conv2: 64->64 ch, 3x3, relu; writes permuted feat ----------------
__global__ __launch_bounds__(256) void conv2_kernel(float* __restrict__ ws)
{
    __align__(16) __shared__ float sT[64 * 156];
    const float* f1  = ws + OFF_F1;
    const float* w2t = ws + OFF_W2T;
    const float* b2f = ws + OFF_B2;
    float* feat = ws + OFF_FEAT;

    int bid = blockIdx.x;            // 4 img * 96 rows * 2 strips = 768
    int img = bid / 192;
    int rem = bid % 192;
    int h  = rem >> 1;
    int s2 = rem & 1;
    int tid = threadIdx.x;

    for (int idx = tid; idx < 9600; idx += 256) {
        int ci = idx / 150;
        int r2 = idx % 150;
        int r = r2 / 50, cc = r2 % 50;
        int row = h - 1 + r, col = s2*48 - 1 + cc;
        float v = 0.f;
        if (row >= 0 && row < 96 && col >= 0 && col < 96)
            v = f1[(size_t)(img*64 + ci)*TOK + row*96 + col];
        sT[ci*156 + r*52 + cc] = v;
    }
    __syncthreads();

    int co = tid & 63, g = tid >> 6;
    int px0 = g * 12;
    float acc[12];
    float bb = b2f[co];
    #pragma unroll
    for (int j = 0; j < 12; ++j) acc[j] = bb;

    for (int ci = 0; ci < 64; ++ci) {
        float wv[9];
        #pragma unroll
        for (int t = 0; t < 9; ++t) wv[t] = w2t[(ci*9 + t)*64 + co];
        #pragma unroll
        for (int r = 0; r < 3; ++r) {
            const float4* tp4 = (const float4*)&sT[ci*156 + r*52 + px0];
            float4 a0 = tp4[0], a1 = tp4[1], a2 = tp4[2], a3 = tp4[3];
            float t16[16] = {a0.x,a0.y,a0.z,a0.w, a1.x,a1.y,a1.z,a1.w,
                             a2.x,a2.y,a2.z,a2.w, a3.x,a3.y,a3.z,a3.w};
            #pragma unroll
            for (int dw = 0; dw < 3; ++dw) {
                float wgt = wv[r*3 + dw];
                #pragma unroll
                for (int j = 0; j < 12; ++j) acc[j] += wgt * t16[j + dw];
            }
        }
    }
    int b = img >> 1, n = img & 1;
    int colbase = s2*48 + px0;
    #pragma unroll
    for (int j = 0; j < 12; ++j)
        feat[(size_t)(b*128 + co*2 + n)*TOK + h*96 + colbase + j] = fmaxf(acc[j], 0.f);
}

// ---------------- fused 1x1 QKV: [192 out][128 in] GEMV per token ----------------
__global__ __launch_bounds__(256) void qkv_kernel(float* __restrict__ ws)
{
    const float* feat = ws + OFF_FEAT;
    const float* wcat = ws + OFF_WCAT;
    const float* bcat = ws + OFF_BCAT;
    int bid = blockIdx.x;            // 2 * 36 * 48 = 3456
    int b   = bid / (36*48);
    int rem = bid % (36*48);
    int tg  = rem / 48;
    int og  = rem % 48;
    int tid = threadIdx.x;
    int o    = og*4 + (tid >> 6);
    int lane = tid & 63;
    int t0   = tg*256 + lane*4;
    const float* fb   = feat + (size_t)b*128*TOK;
    const float* wrow = wcat + o*128;
    float a0, a1, a2, a3;
    a0 = a1 = a2 = a3 = bcat[o];
    for (int c = 0; c < 128; ++c) {
        float4 fv = *(const float4*)&fb[(size_t)c*TOK + t0];
        float w = wrow[c];
        a0 += w*fv.x; a1 += w*fv.y; a2 += w*fv.z; a3 += w*fv.w;
    }
    float* dst;
    if (o < 64)       dst = ws + OFF_Q + ((size_t)b*64 + o      )*TOK;
    else if (o < 128) dst = ws + OFF_K + ((size_t)b*64 + (o-64 ))*TOK;
    else              dst = ws + OFF_V + ((size_t)b*64 + (o-128))*TOK;
    float4 out4 = {a0, a1, a2, a3};
    *(float4*)&dst[t0] = out4;
}

// ---------------- cvt: f32 [d][t] -> f16 tiles for MFMA ----------------
__global__ __launch_bounds__(256) void cvt_kernel(float* __restrict__ ws)
{
    __shared__ __align__(16) float lds[64*68];
    int bid = blockIdx.x;
    int tid = threadIdx.x;
    if (bid < 576) {
        int tensor = bid / 288;          // 0=Q, 1=K
        int rem = bid % 288;
        int b = rem / 144, tile = rem % 144;
        int t0 = tile * 64;
        const float* src = ws + (tensor ? OFF_K : OFF_Q) + (size_t)b*64*TOK;
        _Float16* dst = (_Float16*)(ws + (tensor ? OFF_KT : OFF_QT)) + (size_t)b*TOK*64;
        float scale = tensor ? 1.0f : 0.125f;
        int d = tid >> 2, seg = tid & 3;
        #pragma unroll
        for (int j = 0; j < 4; ++j) {
            float4 v = *(const float4*)&src[(size_t)d*TOK + t0 + seg*16 + j*4];
            *(float4*)&lds[d*68 + seg*16 + j*4] = v;
        }
        __syncthreads();
        int t = tid >> 2, dseg = tid & 3;
        __align__(16) _Float16 h[16];
        #pragma unroll
        for (int e = 0; e < 16; ++e)
            h[e] = (_Float16)(lds[(dseg*16 + e)*68 + t] * scale);
        *(uint4*)&dst[(size_t)(t0 + t)*64 + dseg*16]     = *(uint4*)&h[0];
        *(uint4*)&dst[(size_t)(t0 + t)*64 + dseg*16 + 8] = *(uint4*)&h[8];
    } else {
        size_t idx = (size_t)(bid - 576) * 1024 + tid * 4;   // over 2*64*TOK
        const float* src = ws + OFF_V;
        _Float16* dst = (_Float16*)(ws + OFF_VH);
        float4 v = *(const float4*)&src[idx];
        union { _Float16 h[4]; uint2 u; } pk;
        pk.h[0] = (_Float16)v.x; pk.h[1] = (_Float16)v.y;
        pk.h[2] = (_Float16)v.z; pk.h[3] = (_Float16)v.w;
        *(uint2*)&dst[idx] = pk.u;
    }
}

// ---------------- flash attention partial, f16 MFMA, KV-split ----------------
// grid = 2b x 144qt x KSPLIT; 256 thr = 4 waves x 16 q-rows; KVBLK=64.
// Writes unnormalized O-partial + (m,l) per query row.
__global__ __launch_bounds__(256) void attn_kernel(float* __restrict__ ws)
{
    __shared__ __align__(16) char smem[24576];
    char* sK = smem;            // [64 kt][64 d] f16, byte^((kt&7)<<4)
    char* sV = smem + 8192;     // [64 c ][64 m] f16, byte^((c&7)<<4)
    char* sP = smem + 16384;    // [64 q ][64 m] f16, byte^((q&7)<<4) (wave-private rows)
    float* ldsf = (float*)smem; // epilogue reuse: [64 c][68] f32

    int bid = blockIdx.x;       // 2 * 144 * KSPLIT
    int b   = bid / (144*KSPLIT);
    int rem = bid % (144*KSPLIT);
    int qt  = rem / KSPLIT;
    int ks  = rem % KSPLIT;
    int tid = threadIdx.x;
    int lane = tid & 63, w = tid >> 6;
    int q0 = qt * 64;
    int lr = lane & 15;         // fragment row/col index
    int lk = lane >> 4;         // k-group (0..3)

    const _Float16* Qt = (const _Float16*)(ws + OFF_QT) + (size_t)b*TOK*64;
    const _Float16* Kt = (const _Float16*)(ws + OFF_KT) + (size_t)b*TOK*64;
    const _Float16* Vh = (const _Float16*)(ws + OFF_VH) + (size_t)b*64*TOK;
    float* part = ws + OFF_PART + (size_t)(b*KSPLIT + ks)*64*TOK;
    float* ml   = ws + OFF_ML   + (size_t)(b*KSPLIT + ks)*2*TOK;

    // Q fragments in registers (A: row q = lr, k d = ch*32 + lk*8 + e)
    half8 qA[2];
    #pragma unroll
    for (int ch = 0; ch < 2; ++ch)
        qA[ch] = *(const half8*)&Qt[(size_t)(q0 + w*16 + lr)*64 + ch*32 + lk*8];

    f32x4 O[4];                 // [csub]: col c = csub*16+lr, row q = 4*lk+reg
    #pragma unroll
    for (int cs = 0; cs < 4; ++cs) O[cs] = (f32x4){0.f, 0.f, 0.f, 0.f};
    float mM[4], lS[4];
    #pragma unroll
    for (int r = 0; r < 4; ++r) { mM[r] = -INFINITY; lS[r] = 0.f; }

    int srow = tid >> 3, seg = tid & 7;    // staging coords (srow+32*i)
    int kb0 = ks * KCHUNK;

    // prologue: prefetch tile kb0 into registers
    uint4 kvR[2], vvR[2];
    #pragma unroll
    for (int i = 0; i < 2; ++i) {
        int r2 = srow + 32*i;
        kvR[i] = *(const uint4*)&Kt[(size_t)(kb0*64 + r2)*64 + seg*8];
        vvR[i] = *(const uint4*)&Vh[(size_t)r2*TOK + kb0*64 + seg*8];
    }

    for (int it = 0; it < KCHUNK; ++it) {
        __syncthreads();        // A: prev-iter LDS reads complete
        #pragma unroll
        for (int i = 0; i < 2; ++i) {
            int r2 = srow + 32*i;
            *(uint4*)(sK + ((r2*128 + seg*16) ^ ((r2&7)<<4))) = kvR[i];
            *(uint4*)(sV + ((r2*128 + seg*16) ^ ((r2&7)<<4))) = vvR[i];
        }
        __syncthreads();        // B: staging visible

        // prefetch next tile (overlaps with compute below)
        if (it + 1 < KCHUNK) {
            int kb1 = kb0 + it + 1;
            #pragma unroll
            for (int i = 0; i < 2; ++i) {
                int r2 = srow + 32*i;
                kvR[i] = *(const uint4*)&Kt[(size_t)(kb1*64 + r2)*64 + seg*8];
                vvR[i] = *(const uint4*)&Vh[(size_t)r2*TOK + kb1*64 + seg*8];
            }
        }

        // ---- QK^T: S[q 16][kt 64] per wave ----
        f32x4 S[4];
        #pragma unroll
        for (int st = 0; st < 4; ++st) S[st] = (f32x4){0.f, 0.f, 0.f, 0.f};
        __builtin_amdgcn_s_setprio(1);
        #pragma unroll
        for (int st = 0; st < 4; ++st) {
            int t = st*16 + lr;
            #pragma unroll
            for (int ch = 0; ch < 2; ++ch) {
                half8 kB = *(const half8*)(sK + ((t*128 + ch*64 + lk*16) ^ ((t&7)<<4)));
                S[st] = __builtin_amdgcn_mfma_f32_16x16x32_f16(qA[ch], kB, S[st], 0, 0, 0);
            }
        }
        __builtin_amdgcn_s_setprio(0);

        // ---- online softmax (rows live on 16-lane groups) ----
        float pm[4];
        #pragma unroll
        for (int r = 0; r < 4; ++r)
            pm[r] = fmaxf(fmaxf(S[0][r], S[1][r]), fmaxf(S[2][r], S[3][r]));
        #pragma unroll
        for (int mk = 1; mk <= 8; mk <<= 1)
            #pragma unroll
            for (int r = 0; r < 4; ++r)
                pm[r] = fmaxf(pm[r], __shfl_xor(pm[r], mk));
        float fs[4];
        #pragma unroll
        for (int r = 0; r < 4; ++r) {
            float mn = fmaxf(mM[r], pm[r]);
            fs[r] = __expf(mM[r] - mn);
            mM[r] = mn;
        }
        float p[4][4], ps[4];
        #pragma unroll
        for (int r = 0; r < 4; ++r) ps[r] = 0.f;
        #pragma unroll
        for (int st = 0; st < 4; ++st)
            #pragma unroll
            for (int r = 0; r < 4; ++r) {
                p[st][r] = __expf(S[st][r] - mM[r]);
                ps[r] += p[st][r];
            }
        #pragma unroll
        for (int mk = 1; mk <= 8; mk <<= 1)
            #pragma unroll
            for (int r = 0; r < 4; ++r)
                ps[r] += __shfl_xor(ps[r], mk);
        #pragma unroll
        for (int r = 0; r < 4; ++r) lS[r] = lS[r]*fs[r] + ps[r];
        #pragma unroll
        for (int cs = 0; cs < 4; ++cs)
            #pragma unroll
            for (int r = 0; r < 4; ++r) O[cs][r] *= fs[r];

        // ---- P -> f16 pairs -> swizzled LDS (wave-private rows; no barrier) ----
        #pragma unroll
        for (int st = 0; st < 4; ++st)
            #pragma unroll
            for (int r = 0; r < 4; ++r) {
                union { _Float16 h; unsigned short u; } cv;
                cv.h = (_Float16)p[st][r];
                unsigned int bits = cv.u;
                unsigned int nb = (unsigned int)__shfl_xor((int)bits, 1);
                if ((lane & 1) == 0) {
                    int qrow = w*16 + 4*lk + r;
                    int m = st*16 + lr;          // even
                    *(unsigned int*)(sP + ((qrow*128 + m*2) ^ ((qrow&7)<<4))) =
                        bits | (nb << 16);
                }
            }

        // ---- PV: O[q 16][c 64] += P[16x64] * V^T ----
        __builtin_amdgcn_s_setprio(1);
        #pragma unroll
        for (int ch = 0; ch < 2; ++ch) {
            int qrow = w*16 + lr;
            half8 pA = *(const half8*)(sP + ((qrow*128 + ch*64 + lk*16) ^ ((qrow&7)<<4)));
            #pragma unroll
            for (int cs = 0; cs < 4; ++cs) {
                int crow = cs*16 + lr;
                half8 vB = *(const half8*)(sV + ((crow*128 + ch*64 + lk*16) ^ ((crow&7)<<4)));
                O[cs] = __builtin_amdgcn_mfma_f32_16x16x32_f16(pA, vB, O[cs], 0, 0, 0);
            }
        }
        __builtin_amdgcn_s_setprio(0);
    }

    // ---- write m, l (uniform across each 16-lane group) ----
    if (lr == 0) {
        #pragma unroll
        for (int r = 0; r < 4; ++r) {
            int qrow = w*16 + 4*lk + r;
            ml[q0 + qrow]       = mM[r];
            ml[TOK + q0 + qrow] = lS[r];
        }
    }

    // ---- epilogue: transpose via LDS, coalesced unnormalized partial writes ----
    __syncthreads();
    #pragma unroll
    for (int cs = 0; cs < 4; ++cs)
        #pragma unroll
        for (int r = 0; r < 4; ++r)
            ldsf[(cs*16 + lr)*68 + w*16 + 4*lk + r] = O[cs][r];
    __syncthreads();
    int c = tid >> 2, sg = tid & 3;
    const float* srcr = &ldsf[c*68 + sg*16];
    float* dstr = &part[(size_t)c*TOK + q0 + sg*16];
    #pragma unroll
    for (int j = 0; j < 4; ++j)
        *(float4*)&dstr[j*4] = *(const float4*)&srcr[j*4];
}

// ---------------- recombine KV-split partials ----------------
__global__ __launch_bounds__(256) void recombine_kernel(
    const float* __restrict__ ws, float* __restrict__ out)
{
    int gid = blockIdx.x * 256 + threadIdx.x;   // 2 * 4cg * TOK = 73728
    int b   = gid / (4*TOK);
    int rem = gid % (4*TOK);
    int cg  = rem / TOK;
    int t   = rem % TOK;
    const float* mlp  = ws + OFF_ML;
    const float* part = ws + OFF_PART;

    float m[KSPLIT], l[KSPLIT];
    float M = -INFINITY;
    #pragma unroll
    for (int ks = 0; ks < KSPLIT; ++ks) {
        m[ks] = mlp[(size_t)((b*KSPLIT + ks)*2    )*TOK + t];
        l[ks] = mlp[(size_t)((b*KSPLIT + ks)*2 + 1)*TOK + t];
        M = fmaxf(M, m[ks]);
    }
    float wgt[KSPLIT];
    float denom = 0.f;
    #pragma unroll
    for (int ks = 0; ks < KSPLIT; ++ks) {
        wgt[ks] = __expf(m[ks] - M);
        denom += l[ks] * wgt[ks];
    }
    float inv = 1.f / denom;
    #pragma unroll
    for (int cc = 0; cc < 16; ++cc) {
        int c = cg*16 + cc;
        float acc = 0.f;
        #pragma unroll
        for (int ks = 0; ks < KSPLIT; ++ks)
            acc += part[(size_t)((b*KSPLIT + ks)*64 + c)*TOK + t] * wgt[ks];
        out[(size_t)(b*64 + c)*TOK + t] = acc * inv;
    }
}

extern "C" void kernel_launch(void* const* d_in, const int* in_sizes, int n_in,
                              void* d_out, int out_size, void* d_ws, size_t ws_size,
                              hipStream_t stream)
{
    const float* frames = (const float*)d_in[0];
    const float* w1 = (const float*)d_in[1];
    const float* b1 = (const float*)d_in[2];
    const float* w2 = (const float*)d_in[3];
    const float* b2 = (const float*)d_in[4];
    const float* qw = (const float*)d_in[5];
    const float* qb = (const float*)d_in[6];
    const float* kw = (const float*)d_in[7];
    const float* kb = (const float*)d_in[8];
    const float* vw = (const float*)d_in[9];
    const float* vb = (const float*)d_in[10];
    float* ws = (float*)d_ws;
    float* out = (float*)d_out;

    hipLaunchKernelGGL(prep_kernel, dim3(144), dim3(256), 0, stream,
                       w1, b1, w2, b2, qw, qb, kw, kb, vw, vb, ws);
    hipLaunchKernelGGL(conv1_kernel, dim3(144), dim3(256), 0, stream, frames, ws);
    hipLaunchKernelGGL(conv2_kernel, dim3(768), dim3(256), 0, stream, ws);
    hipLaunchKernelGGL(qkv_kernel, dim3(3456), dim3(256), 0, stream, ws);
    hipLaunchKernelGGL(cvt_kernel, dim3(1728), dim3(256), 0, stream, ws);
    hipLaunchKernelGGL(attn_kernel, dim3(2*144*KSPLIT), dim3(256), 0, stream, ws);
    hipLaunchKernelGGL(recombine_kernel, dim3(288), dim3(256), 0, stream, ws, out);
}